// Round 16
// baseline (108.524 us; speedup 1.0000x reference)
//
#include <hip/hip_runtime.h>

#define BATCH  65536
#define NIN    9
#define NHID   100
#define TSTEPS 25
#define CHUNK  5
#define EPS    3e-5f

typedef float v2f __attribute__((ext_vector_type(2)));

// ROUND-16: spike-bitmask two-phase structure. The r2-r15 plateau (~44us,
// ~14 inst/neuron-step implied) is the AGPR-resident acc[50] array being
// touched twice per step (accvgpr read/write brackets). Here the hot chain
// touches NO array: phase 1 packs each neuron's 25 spike bits into floats
// (ma/mb += d*2^t, exact) -> LDS; phase 2 (t outer) rebuilds acc as two
// SCALARS from mask bits. Decisions: f32 u-chain (u=m-1) with margin
// tracking; wave-uniform f64 fallback (the exact r2 chain) rebuilds the
// mask when any lane is within EPS -> spike trains identical to the f64
// arbiter-tracking chain; fc2 fmac order (ascending j) identical to r10-15
// -> output bit-identical (absmax 0.1015625).
__global__ __launch_bounds__(256) void snn_kernel(
    const float* __restrict__ x,  const float* __restrict__ W1,
    const float* __restrict__ b1, const float* __restrict__ W2,
    const float* __restrict__ b2, float* __restrict__ out)
{
    __shared__ float    sx[64 * NIN];            // 2.25 KB staged x rows
    __shared__ unsigned smsk[4][25][64];         // 25.6 KB spike masks
    __shared__ v2f      sacc[2][4][CHUNK][64];   // 20.5 KB reduce buffers

    const int tid  = threadIdx.x;
    const int lane = tid & 63;
    const int wq   = __builtin_amdgcn_readfirstlane(tid >> 6);
    const int b0   = blockIdx.x * 64;

    for (int i = tid; i < 64 * NIN; i += 256) sx[i] = x[(size_t)b0 * NIN + i];
    __syncthreads();

    float xv[NIN];
#pragma unroll
    for (int i = 0; i < NIN; ++i) xv[i] = sx[lane * NIN + i];

    const int h0 = wq * 25;

    // ---------------- phase 1: spike masks ----------------
#pragma unroll 1
    for (int j = 0; j < 25; ++j) {
        const int h = h0 + j;                  // wave-uniform -> s_load weights
        float c32 = 0.f;
#pragma unroll
        for (int i = 0; i < NIN; ++i) c32 = fmaf(W1[h * NIN + i], xv[i], c32);
        c32 += b1[h];
        const float k  = c32 - 0.05f;          // u-chain: u = m-1
        const float k1 = c32 - 1.05f;

        float u = -1.0f, ming = 1e30f, ma = 0.f, mb = 0.f;
        bool  s = false;
#pragma unroll
        for (int t = 0; t < TSTEPS; ++t) {
            u = fmaf(0.95f, u, s ? k1 : k);    // leaky integrate + fused reset
            s = (u > 0.0f);                    // spike (== m > 1)
            ming = fminf(ming, fabsf(u));      // margin (abs modifier free)
            float d = s ? 1.f : 0.f;
            if (t < 13) ma = fmaf(d, (float)(1u << t),        ma);
            else        mb = fmaf(d, (float)(1u << (t - 13)), mb);
        }

        // rare wave-uniform exact fallback: rebuild mask from the f64 chain
        // (bit-identical to rounds 2-15 -> tracks the numpy f64 arbiter)
        if (__any(ming < EPS)) {
            double c64 = 0.0;
#pragma unroll
            for (int i = 0; i < NIN; ++i)
                c64 += (double)W1[h * NIN + i] * (double)xv[i];
            c64 += (double)b1[h];
            const double c1 = c64 - 1.0;
            double md = 0.0;  bool sd = false;
            ma = 0.f;  mb = 0.f;
#pragma unroll
            for (int t = 0; t < TSTEPS; ++t) {
                md = 0.95 * md + (sd ? c1 : c64);
                sd = (md > 1.0);
                float d = sd ? 1.f : 0.f;
                if (t < 13) ma = fmaf(d, (float)(1u << t),        ma);
                else        mb = fmaf(d, (float)(1u << (t - 13)), mb);
            }
        }
        smsk[wq][j][lane] = (unsigned)ma | ((unsigned)mb << 13);
    }

    // W2 columns (wave-uniform -> SGPR-resident); compile-time j indices
    float w0s[25], w1s[25];
#pragma unroll
    for (int j = 0; j < 25; ++j) {
        w0s[j] = W2[h0 + j];
        w1s[j] = W2[NHID + h0 + j];
    }

    // masks back to registers with compile-time indices (round-9 lesson:
    // no dynamically-indexed register arrays, ever)
    unsigned mr[25];
#pragma unroll
    for (int j = 0; j < 25; ++j) mr[j] = smsk[wq][j][lane];

    // ---------------- phase 2: fc2 + reduce + mem2 ----------------
    double m20 = 0.0, m21 = 0.0;
    double bb0 = (double)b2[0], bb1 = (double)b2[1];

#pragma unroll
    for (int kc = 0; kc < TSTEPS / CHUNK; ++kc) {
#pragma unroll
        for (int uu = 0; uu < CHUNK; ++uu) {
            const int t = kc * CHUNK + uu;
            float a0 = 0.f, a1 = 0.f;          // SCALAR accumulators
#pragma unroll
            for (int j = 0; j < 25; ++j) {     // ascending j == r10-15 order
                float d = (float)((mr[j] >> t) & 1u);
                a0 = fmaf(d, w0s[j], a0);
                a1 = fmaf(d, w1s[j], a1);
            }
            sacc[kc & 1][wq][uu][lane] = (v2f){a0, a1};
        }
        __syncthreads();
        // wave0 reads buf[kc&1] before the NEXT barrier; other waves can't
        // overwrite buf[kc&1] until chunk kc+2's writes, behind that barrier.
        if (wq == 0) {
#pragma unroll
            for (int uu = 0; uu < CHUNK; ++uu) {
                const int t = kc * CHUNK + uu;
                v2f q0 = sacc[kc & 1][0][uu][lane];
                v2f q1 = sacc[kc & 1][1][uu][lane];
                v2f q2 = sacc[kc & 1][2][uu][lane];
                v2f q3 = sacc[kc & 1][3][uu][lane];
                v2f sum = (q0 + q1) + (q2 + q3);   // butterfly bracketing
                double r0 = (m20 > 1.0) ? 1.0 : 0.0;
                double r1 = (m21 > 1.0) ? 1.0 : 0.0;
                m20 = 0.95 * m20 + ((double)sum[0] + bb0) - r0;
                m21 = 0.95 * m21 + ((double)sum[1] + bb1) - r1;
                *(float2*)(out + ((size_t)t * BATCH + b0 + lane) * 2) =
                    make_float2((float)m20, (float)m21);
            }
        }
    }
}

extern "C" void kernel_launch(void* const* d_in, const int* in_sizes, int n_in,
                              void* d_out, int out_size, void* d_ws, size_t ws_size,
                              hipStream_t stream) {
    const float* x  = (const float*)d_in[0];
    const float* W1 = (const float*)d_in[1];
    const float* b1 = (const float*)d_in[2];
    const float* W2 = (const float*)d_in[3];
    const float* b2 = (const float*)d_in[4];
    float* out = (float*)d_out;

    dim3 grid(BATCH / 64), block(256);
    hipLaunchKernelGGL(snn_kernel, grid, block, 0, stream, x, W1, b1, W2, b2, out);
}

// Round 17
// 97.977 us; speedup vs baseline: 1.1077x; 1.1077x over previous
//
#include <hip/hip_runtime.h>

#define BATCH  65536
#define NIN    9
#define NHID   100
#define TSTEPS 25
#define CHUNK  5
#define EPS    3e-5f

typedef float v2f __attribute__((ext_vector_type(2)));

// ROUND-17: the decisive combo. CDNA4 vector FP64 is HALF-RATE (MI355X
// ~78.6 TF f64 vs 157 TF f32): r10's f64 m-chain cost ~22 cyc/step, which
// matches measured busy exactly — the kernel is issue-bound, and the f64
// chain was double-priced. r15's f32 chain didn't win because its v2f
// accumulator codegen added moves. Here: f32 u-chain (u = m-1) with margin
// tracking + exact-f64 wave-uniform fallback (r15/16 machinery, both passed
// bit-identical) + SCALAR float accumulators via fmaf (r10-14 style, never
// showed acc overhead). Model: 14 cyc/step vs r10's 22.
__global__ __launch_bounds__(256) void snn_kernel(
    const float* __restrict__ x,  const float* __restrict__ W1,
    const float* __restrict__ b1, const float* __restrict__ W2,
    const float* __restrict__ b2, float* __restrict__ out)
{
    __shared__ float sx[64 * NIN];              // 2.25 KB staged x rows
    __shared__ v2f   sacc[2][4][CHUNK][64];     // 20.5 KB double-buffered reduce

    const int tid  = threadIdx.x;
    const int lane = tid & 63;
    const int wq   = __builtin_amdgcn_readfirstlane(tid >> 6);
    const int b0   = blockIdx.x * 64;

    for (int i = tid; i < 64 * NIN; i += 256) sx[i] = x[(size_t)b0 * NIN + i];
    __syncthreads();

    // per-lane x row, f32 (exact input values)
    float xv[NIN];
#pragma unroll
    for (int i = 0; i < NIN; ++i) xv[i] = sx[lane * NIN + i];

    // per-step fc2 partial sums: SCALAR floats (no v2f, no f64)
    float a0[TSTEPS], a1[TSTEPS];
#pragma unroll
    for (int t = 0; t < TSTEPS; ++t) { a0[t] = 0.f; a1[t] = 0.f; }

    const int h0 = wq * 25;
#pragma unroll 1
    for (int j = 0; j < 25; ++j) {
        const int h = h0 + j;                  // wave-uniform -> s_load weights
        float c32 = 0.f;
#pragma unroll
        for (int i = 0; i < NIN; ++i) c32 = fmaf(W1[h * NIN + i], xv[i], c32);
        c32 += b1[h];
        const float k  = c32 - 0.05f;          // u-chain: u = m-1
        const float k1 = c32 - 1.05f;
        const float w0 = W2[h], w1 = W2[NHID + h];

        float u = -1.0f, ming = 1e30f;
        bool  s = false;                       // spike(t-1) == reset(t)
#pragma unroll
        for (int t = 0; t < TSTEPS; ++t) {
            u = fmaf(0.95f, u, s ? k1 : k);    // leaky integrate + fused reset
            s = (u > 0.0f);                    // spike (== m > 1)
            ming = fminf(ming, fabsf(u));      // margin (abs modifier free)
            float d = s ? 1.f : 0.f;
            a0[t] = fmaf(d, w0, a0[t]);
            a1[t] = fmaf(d, w1, a1[t]);
        }

        // rare wave-uniform exact fallback: f32 replay (bit-identical: same
        // fmaf sequence, same inputs) vs the EXACT f64 chain of rounds 2-14;
        // patch acc where decisions differ -> spike trains track the f64
        // numpy arbiter everywhere.
        if (__any(ming < EPS)) {
            double c64 = 0.0;
#pragma unroll
            for (int i = 0; i < NIN; ++i)
                c64 += (double)W1[h * NIN + i] * (double)xv[i];
            c64 += (double)b1[h];
            const double c1 = c64 - 1.0;

            double md = 0.0;  bool sd = false;   // exact f64 chain
            float  ur = -1.0f; bool sr = false;  // f32 replay
#pragma unroll
            for (int t = 0; t < TSTEPS; ++t) {
                ur = fmaf(0.95f, ur, sr ? k1 : k);
                sr = (ur > 0.0f);
                md = 0.95 * md + (sd ? c1 : c64);
                sd = (md > 1.0);
                if (sr != sd) {                  // patch to the f64 decision
                    float sg = sd ? 1.f : -1.f;
                    a0[t] = fmaf(sg, w0, a0[t]);
                    a1[t] = fmaf(sg, w1, a1[t]);
                }
            }
        }
    }

    // chunked cross-wave reduce + mem2 (wave 0), double-buffered LDS.
    // All acc indices compile-time constants (round-9 lesson).
    double m20 = 0.0, m21 = 0.0;
    double bb0 = (double)b2[0], bb1 = (double)b2[1];

#pragma unroll
    for (int k = 0; k < TSTEPS / CHUNK; ++k) {
#pragma unroll
        for (int u = 0; u < CHUNK; ++u)
            sacc[k & 1][wq][u][lane] = (v2f){a0[k * CHUNK + u], a1[k * CHUNK + u]};
        __syncthreads();
        // wave0 reads buf[k&1] before the NEXT barrier; other waves can't
        // overwrite buf[k&1] until chunk k+2's writes, behind that barrier.
        if (wq == 0) {
#pragma unroll
            for (int u = 0; u < CHUNK; ++u) {
                const int t = k * CHUNK + u;
                v2f q0 = sacc[k & 1][0][u][lane];
                v2f q1 = sacc[k & 1][1][u][lane];
                v2f q2 = sacc[k & 1][2][u][lane];
                v2f q3 = sacc[k & 1][3][u][lane];
                v2f sum = (q0 + q1) + (q2 + q3);   // butterfly bracketing
                double r0 = (m20 > 1.0) ? 1.0 : 0.0;
                double r1 = (m21 > 1.0) ? 1.0 : 0.0;
                m20 = 0.95 * m20 + ((double)sum[0] + bb0) - r0;
                m21 = 0.95 * m21 + ((double)sum[1] + bb1) - r1;
                *(float2*)(out + ((size_t)t * BATCH + b0 + lane) * 2) =
                    make_float2((float)m20, (float)m21);
            }
        }
    }
}

extern "C" void kernel_launch(void* const* d_in, const int* in_sizes, int n_in,
                              void* d_out, int out_size, void* d_ws, size_t ws_size,
                              hipStream_t stream) {
    const float* x  = (const float*)d_in[0];
    const float* W1 = (const float*)d_in[1];
    const float* b1 = (const float*)d_in[2];
    const float* W2 = (const float*)d_in[3];
    const float* b2 = (const float*)d_in[4];
    float* out = (float*)d_out;

    dim3 grid(BATCH / 64), block(256);
    hipLaunchKernelGGL(snn_kernel, grid, block, 0, stream, x, W1, b1, W2, b2, out);
}